// Round 5
// baseline (358.373 us; speedup 1.0000x reference)
//
#include <hip/hip_runtime.h>
#include <hip/hip_bf16.h>

#define N_NODES    50000
#define DIM        128
#define NUM_GRAPHS 64
#define NUM_CLASSES 3
#define NPAD       50176   // 196*256
#define XPITCH     136     // LDS row pitch in ushorts (17 x 16B, odd -> conflict-free b128)

typedef unsigned short ushort_t;
typedef unsigned int   uint_t;
typedef __attribute__((ext_vector_type(8))) short short8;
typedef __attribute__((ext_vector_type(4))) float f32x4;

__device__ __forceinline__ ushort_t f2bf(float f) {
    union { float f; uint_t u; } v; v.f = f;
    uint_t r = v.u + 0x7fffu + ((v.u >> 16) & 1u);   // RNE
    return (ushort_t)(r >> 16);
}
__device__ __forceinline__ float bflo(uint_t u) {
    union { uint_t u; float f; } v; v.u = u << 16; return v.f;
}
__device__ __forceinline__ float bfhi(uint_t u) {
    union { uint_t u; float f; } v; v.u = u & 0xffff0000u; return v.f;
}

// raw gather, software-pipelined. PROVEN round-0 core (303 us) -- rounds 1/3/4
// showed restructuring (wide-x4, shuffle-idx, 1-node/wave TLP) all regress.
__device__ __forceinline__ void gather_raw(
    int n, int lane, const int* __restrict__ rowptr,
    const int* __restrict__ csr_src, const uint_t* __restrict__ Tb,
    float2& acc)
{
    int p0 = rowptr[n], p1 = rowptr[n + 1];
    uint_t us = Tb[n * 64 + lane];      // self loop
    float2 a0 = make_float2(bflo(us), bfhi(us));
    float2 a1 = make_float2(0.f, 0.f);
    int p = p0;
    int nb = (p1 - p0) >> 3;            // full 8-batches
    if (nb > 0) {
        uint_t ucur[8];
        #pragma unroll
        for (int q = 0; q < 8; ++q) ucur[q] = Tb[csr_src[p + q] * 64 + lane];
        for (int b = 1; b < nb; ++b) {
            uint_t unxt[8];
            #pragma unroll
            for (int q = 0; q < 8; ++q) unxt[q] = Tb[csr_src[p + 8 + q] * 64 + lane];
            #pragma unroll
            for (int q = 0; q < 8; q += 2) {
                a0.x += bflo(ucur[q]);     a0.y += bfhi(ucur[q]);
                a1.x += bflo(ucur[q + 1]); a1.y += bfhi(ucur[q + 1]);
            }
            #pragma unroll
            for (int q = 0; q < 8; ++q) ucur[q] = unxt[q];
            p += 8;
        }
        #pragma unroll
        for (int q = 0; q < 8; q += 2) {
            a0.x += bflo(ucur[q]);     a0.y += bfhi(ucur[q]);
            a1.x += bflo(ucur[q + 1]); a1.y += bfhi(ucur[q + 1]);
        }
        p += 8;
    }
    for (; p + 4 <= p1; p += 4) {
        int s[4]; uint_t u[4];
        #pragma unroll
        for (int q = 0; q < 4; ++q) s[q] = csr_src[p + q];
        #pragma unroll
        for (int q = 0; q < 4; ++q) u[q] = Tb[s[q] * 64 + lane];
        #pragma unroll
        for (int q = 0; q < 4; q += 2) {
            a0.x += bflo(u[q]);     a0.y += bfhi(u[q]);
            a1.x += bflo(u[q + 1]); a1.y += bfhi(u[q + 1]);
        }
    }
    for (; p < p1; ++p) {
        int s = csr_src[p];
        uint_t u = Tb[s * 64 + lane];
        a0.x += bflo(u); a0.y += bfhi(u);
    }
    acc.x += a0.x + a1.x;
    acc.y += a0.y + a1.y;
}

// ---------------- init ----------------
__global__ void k_init(int* degi, float* pooled, float* counts) {
    int i = blockIdx.x * 256 + threadIdx.x;
    if (i < NPAD) degi[i] = 0;
    if (i < NUM_GRAPHS * DIM) pooled[i] = 0.0f;
    if (i < NUM_GRAPHS) counts[i] = 0.0f;
}

// zero W_gs (64 x NPAD floats) -- 3136 blocks x 256 thr x float4
__global__ void k_init_wgs(float* Wgs) {
    int i = blockIdx.x * 256 + threadIdx.x;
    ((float4*)Wgs)[i] = make_float4(0.f, 0.f, 0.f, 0.f);
}

// ---------------- W -> Wt bf16 transpose (all 3 layers) ----------------
__global__ void k_prep(const float* __restrict__ W1, const float* __restrict__ W2,
                       const float* __restrict__ W3, ushort_t* __restrict__ Wt) {
    int i = blockIdx.x * 256 + threadIdx.x;
    int mat = i >> 14;
    int idx = i & 16383;
    const float* W = (mat == 0) ? W1 : (mat == 1) ? W2 : W3;
    int n = idx >> 7, k = idx & 127;
    Wt[mat * 16384 + n * 128 + k] = f2bf(W[k * 128 + n]);
}

// ---------------- degree histogram; atomic return = within-row rank ----------------
__global__ void k_count(const int* __restrict__ dst, int* degi, int* rank, int nedges) {
    int e = blockIdx.x * 256 + threadIdx.x;
    if (e < nedges) rank[e] = atomicAdd(&degi[dst[e]], 1);
}

// ---------------- scan ----------------
__global__ __launch_bounds__(256) void k_scan1(const int* __restrict__ degi,
                                               int* rowptr, int* bsum) {
    __shared__ int sh[256];
    int i = blockIdx.x * 256 + threadIdx.x;
    int v = degi[i];
    sh[threadIdx.x] = v;
    __syncthreads();
    for (int off = 1; off < 256; off <<= 1) {
        int t = (threadIdx.x >= off) ? sh[threadIdx.x - off] : 0;
        __syncthreads();
        sh[threadIdx.x] += t;
        __syncthreads();
    }
    rowptr[i] = sh[threadIdx.x] - v;
    if (threadIdx.x == 255) bsum[blockIdx.x] = sh[255];
}

__global__ __launch_bounds__(256) void k_scan2(int* bsum, int nblocks) {
    __shared__ int sh[256];
    int v = (threadIdx.x < nblocks) ? bsum[threadIdx.x] : 0;
    sh[threadIdx.x] = v;
    __syncthreads();
    for (int off = 1; off < 256; off <<= 1) {
        int t = (threadIdx.x >= off) ? sh[threadIdx.x - off] : 0;
        __syncthreads();
        sh[threadIdx.x] += t;
        __syncthreads();
    }
    if (threadIdx.x < nblocks) bsum[threadIdx.x] = sh[threadIdx.x] - v;
}

__global__ __launch_bounds__(256) void k_scan3(int* rowptr, const int* __restrict__ bsum,
                                               const int* __restrict__ degi,
                                               float* dinv) {
    int i = blockIdx.x * 256 + threadIdx.x;
    rowptr[i] = rowptr[i] + bsum[blockIdx.x];
    if (i < N_NODES) dinv[i] = rsqrtf((float)degi[i] + 1.0f);
}

// ---------------- CSR fill: atomic-free scatter via precomputed rank ----------------
__global__ void k_fill(const int* __restrict__ src, const int* __restrict__ dst,
                       const int* __restrict__ rank, const int* __restrict__ rowptr,
                       int* csr_src, int nedges) {
    int e = blockIdx.x * 256 + threadIdx.x;
    if (e < nedges) csr_src[rowptr[dst[e]] + rank[e]] = src[e];
}

// ---------------- W_gs build: edge term. W_gs[g][s] += dinv[dst] ----------------
__global__ void k_wgs_e(const int* __restrict__ src, const int* __restrict__ dst,
                        const int* __restrict__ batch, const float* __restrict__ dinv,
                        float* Wgs, int nedges) {
    int e = blockIdx.x * 256 + threadIdx.x;
    if (e < nedges) {
        int n = dst[e];
        int g = batch[n];
        atomicAdd(&Wgs[g * NPAD + src[e]], dinv[n]);
    }
}

// ---------------- W_gs self term + node counts ----------------
__global__ __launch_bounds__(256) void k_wgs_n(const int* __restrict__ batch,
                                               const float* __restrict__ dinv,
                                               float* Wgs, float* counts) {
    __shared__ float lh[NUM_GRAPHS];
    int tid = threadIdx.x;
    int i = blockIdx.x * 256 + tid;
    if (tid < NUM_GRAPHS) lh[tid] = 0.f;
    __syncthreads();
    if (i < N_NODES) {
        int g = batch[i];
        atomicAdd(&Wgs[g * NPAD + i], dinv[i]);
        atomicAdd(&lh[g], 1.0f);
    }
    __syncthreads();
    if (tid < NUM_GRAPHS && lh[tid] != 0.f) atomicAdd(&counts[tid], lh[tid]);
}

// ---------------- layer-1 matmul: Tb1' = (x @ W1) * dinv[row] ----------------
__global__ __launch_bounds__(256) void k_mm1(
    const float* __restrict__ xin, const ushort_t* __restrict__ WtG,
    const float* __restrict__ dinv, ushort_t* __restrict__ TbOut)
{
    __shared__ ushort_t Wl[DIM * XPITCH];
    __shared__ ushort_t Xl[64 * XPITCH];

    const int tid = threadIdx.x;
    const int rowbase = blockIdx.x * 64;

    #pragma unroll
    for (int i = 0; i < 8; ++i) {
        int g = tid + i * 256;
        uint4 v = ((const uint4*)WtG)[g];
        *((uint4*)&Wl[(g >> 4) * XPITCH + (g & 15) * 8]) = v;
    }
    #pragma unroll
    for (int i = 0; i < 8; ++i) {
        int c = tid + i * 256;
        int row = c >> 5;
        int grow = rowbase + row;
        float4 f = make_float4(0.f, 0.f, 0.f, 0.f);
        if (grow < N_NODES)
            f = ((const float4*)xin)[(long long)rowbase * 32 + c];
        ushort4 h;
        h.x = f2bf(f.x); h.y = f2bf(f.y); h.z = f2bf(f.z); h.w = f2bf(f.w);
        *((ushort4*)&Xl[row * XPITCH + (c & 31) * 4]) = h;
    }
    __syncthreads();

    const int wave = tid >> 6;
    const int lane = tid & 63;
    const int quad = lane >> 4;
    const int lm   = lane & 15;
    const int m0   = wave * 16;

    short8 af[4];
    #pragma unroll
    for (int k0 = 0; k0 < 4; ++k0)
        af[k0] = *(const short8*)&Xl[(m0 + lm) * XPITCH + k0 * 32 + quad * 8];

    int noder[4]; float di[4]; bool okr[4];
    #pragma unroll
    for (int r = 0; r < 4; ++r) {
        noder[r] = rowbase + m0 + quad * 4 + r;
        okr[r] = (noder[r] < N_NODES);
        di[r] = okr[r] ? dinv[noder[r]] : 0.f;
    }

    for (int n0 = 0; n0 < DIM; n0 += 16) {
        f32x4 acc = {0.f, 0.f, 0.f, 0.f};
        #pragma unroll
        for (int k0 = 0; k0 < 4; ++k0) {
            short8 bf = *(const short8*)&Wl[(n0 + lm) * XPITCH + k0 * 32 + quad * 8];
            acc = __builtin_amdgcn_mfma_f32_16x16x32_bf16(af[k0], bf, acc, 0, 0, 0);
        }
        int n = n0 + lm;
        #pragma unroll
        for (int r = 0; r < 4; ++r)
            if (okr[r])
                TbOut[(long long)noder[r] * DIM + n] = f2bf(acc[r] * di[r]);
    }
}

// ---------------- fused: X = ReLU(b + dinv[n]*Sum Tb'[s]) ; Tb_out' = (X@W)*dinv ----------------
// EXACT round-0 proven version (45.4 us).
__global__ __launch_bounds__(256) void k_fused(
    const int* __restrict__ rowptr, const int* __restrict__ csr_src,
    const float* __restrict__ dinv, const uint_t* __restrict__ TbIn,
    const ushort_t* __restrict__ WtG, const float* __restrict__ b_prev,
    ushort_t* __restrict__ TbOut)
{
    __shared__ ushort_t Xl[16 * XPITCH];   // 4352 B

    const int tid = threadIdx.x;
    const int rowbase = blockIdx.x * 16;
    const int wave = tid >> 6;
    const int lane = tid & 63;

    float2 bias2 = ((const float2*)b_prev)[lane];

    #pragma unroll
    for (int t = 0; t < 4; ++t) {
        int r = wave * 4 + t;
        int n = rowbase + r;
        float2 acc = make_float2(0.f, 0.f);
        float dd = 0.f;
        if (n < N_NODES) {
            dd = dinv[n];
            gather_raw(n, lane, rowptr, csr_src, TbIn, acc);
        }
        ushort2 h;
        h.x = f2bf(fmaxf(bias2.x + acc.x * dd, 0.f));
        h.y = f2bf(fmaxf(bias2.y + acc.y * dd, 0.f));
        *((ushort2*)&Xl[r * XPITCH + lane * 2]) = h;
    }
    __syncthreads();

    const int quad = lane >> 4;
    const int lm   = lane & 15;

    short8 af[4];
    #pragma unroll
    for (int k0 = 0; k0 < 4; ++k0)
        af[k0] = *(const short8*)&Xl[lm * XPITCH + k0 * 32 + quad * 8];

    int noder[4]; float di[4]; bool okr[4];
    #pragma unroll
    for (int r = 0; r < 4; ++r) {
        noder[r] = rowbase + quad * 4 + r;
        okr[r] = (noder[r] < N_NODES);
        di[r] = okr[r] ? dinv[noder[r]] : 0.f;
    }

    #pragma unroll
    for (int h = 0; h < 2; ++h) {
        int n0 = wave * 32 + h * 16;
        f32x4 acc = {0.f, 0.f, 0.f, 0.f};
        #pragma unroll
        for (int k0 = 0; k0 < 4; ++k0) {
            short8 bf = *(const short8*)&WtG[(n0 + lm) * DIM + k0 * 32 + quad * 8];
            acc = __builtin_amdgcn_mfma_f32_16x16x32_bf16(af[k0], bf, acc, 0, 0, 0);
        }
        int n = n0 + lm;
        #pragma unroll
        for (int r = 0; r < 4; ++r)
            if (okr[r])
                TbOut[(long long)noder[r] * DIM + n] = f2bf(acc[r] * di[r]);
    }
}

// ---------------- pooled = W_gs @ Y  (skip-scan sparse-row GEMM) ----------------
// Replaces the third gather+pool: mean-pool commutes with the (linear) layer-3
// aggregation. grid(64 graphs, 49 chunks); blockIdx.x = graph so the 64 blocks
// of one chunk run concurrently and share the Y chunk in L2. Each wave scans
// 256 consecutive s: wave-uniform w (float4 loads, L1-resident), row load only
// when w!=0 (~23% dense). No index->row dependent chain, monotonic addresses.
__global__ __launch_bounds__(256) void k_poolmm(
    const float* __restrict__ Wgs, const uint_t* __restrict__ Y,
    float* pooled)
{
    __shared__ float lsum[DIM];

    const int tid  = threadIdx.x;
    const int wave = tid >> 6;
    const int lane = tid & 63;
    const int g    = blockIdx.x;
    const int s0   = blockIdx.y * 1024 + wave * 256;

    if (tid < DIM) lsum[tid] = 0.f;
    __syncthreads();

    const float* wrow = Wgs + g * NPAD + s0;
    float2 acc = make_float2(0.f, 0.f);

    for (int i0 = 0; i0 < 256; i0 += 16) {
        float4 w0 = *(const float4*)(wrow + i0);
        float4 w1 = *(const float4*)(wrow + i0 + 4);
        float4 w2 = *(const float4*)(wrow + i0 + 8);
        float4 w3 = *(const float4*)(wrow + i0 + 12);
        float w[16] = {w0.x, w0.y, w0.z, w0.w, w1.x, w1.y, w1.z, w1.w,
                       w2.x, w2.y, w2.z, w2.w, w3.x, w3.y, w3.z, w3.w};
        uint_t u[16];
        #pragma unroll
        for (int q = 0; q < 16; ++q) {
            u[q] = 0u;
            if (w[q] != 0.f) u[q] = Y[(s0 + i0 + q) * 64 + lane];
        }
        #pragma unroll
        for (int q = 0; q < 16; ++q) {
            acc.x += w[q] * bflo(u[q]);
            acc.y += w[q] * bfhi(u[q]);
        }
    }

    atomicAdd(&lsum[2 * lane], acc.x);
    atomicAdd(&lsum[2 * lane + 1], acc.y);
    __syncthreads();
    if (tid < DIM && lsum[tid] != 0.f)
        atomicAdd(&pooled[g * DIM + tid], lsum[tid]);
}

// ---------------- classifier head (adds b3 after the mean) ----------------
__global__ __launch_bounds__(128) void k_cls(
    const float* __restrict__ pooled, const float* __restrict__ counts,
    const float* __restrict__ b3,
    const float* __restrict__ C1, const float* __restrict__ bc1,
    const float* __restrict__ C2, const float* __restrict__ bc2,
    float* out)
{
    __shared__ float pm[DIM];
    __shared__ float gv[DIM];
    int g = blockIdx.x, j = threadIdx.x;
    float cnt = fmaxf(counts[g], 1.0f);
    pm[j] = pooled[g * DIM + j] / cnt + b3[j];
    __syncthreads();
    float a = bc1[j];
    for (int k = 0; k < DIM; ++k) a += pm[k] * C1[k * DIM + j];
    gv[j] = fmaxf(a, 0.f);
    __syncthreads();
    if (j < NUM_CLASSES) {
        float o = bc2[j];
        for (int k = 0; k < DIM; ++k) o += gv[k] * C2[k * NUM_CLASSES + j];
        out[g * NUM_CLASSES + j] = o;
    }
}

extern "C" void kernel_launch(void* const* d_in, const int* in_sizes, int n_in,
                              void* d_out, int out_size, void* d_ws, size_t ws_size,
                              hipStream_t stream) {
    const float* x    = (const float*)d_in[0];
    const int*   ei   = (const int*)d_in[1];
    const int*   batch= (const int*)d_in[2];
    const float* W1   = (const float*)d_in[3];
    const float* b1   = (const float*)d_in[4];
    const float* W2   = (const float*)d_in[5];
    const float* b2   = (const float*)d_in[6];
    const float* W3   = (const float*)d_in[7];
    const float* b3   = (const float*)d_in[8];
    const float* C1   = (const float*)d_in[9];
    const float* bc1  = (const float*)d_in[10];
    const float* C2   = (const float*)d_in[11];
    const float* bc2  = (const float*)d_in[12];

    const int nedges = in_sizes[1] / 2;
    const int* src = ei;
    const int* dst = ei + nedges;

    // workspace layout (4-byte units)
    float*    dinv    = (float*)d_ws;                           // NPAD
    uint_t*   TbA     = (uint_t*)(dinv + NPAD);                 // N_NODES*64
    uint_t*   TbB     = TbA + (long long)N_NODES * 64;          // N_NODES*64
    float*    pooled  = (float*)(TbB + (long long)N_NODES * 64);// 8192
    float*    counts  = pooled + NUM_GRAPHS * DIM;              // 64
    int*      degi    = (int*)(counts + 64);                    // NPAD
    int*      rowptr  = degi + NPAD;                            // NPAD+256
    int*      bsum    = rowptr + NPAD + 256;                    // 256
    int*      rank    = bsum + 256;                             // nedges
    int*      csr_src = rank + nedges;                          // nedges
    ushort_t* Wt      = (ushort_t*)(csr_src + nedges);          // 3*16384 bf16
    float*    Wgs     = (float*)(Wt + 3 * 16384);               // 64*NPAD floats (12.8 MB)

    const int nodeBlocks = NPAD / 256;                     // 196
    const int mmBlocks   = (N_NODES + 63) / 64;            // 782
    const int fusedBlocks= (N_NODES + 15) / 16;            // 3125
    const int edgeBlocks = (nedges + 255) / 256;           // 3125
    const int wgsBlocks  = NUM_GRAPHS * NPAD / 4 / 256;    // 3136

    k_init<<<nodeBlocks, 256, 0, stream>>>(degi, pooled, counts);
    k_init_wgs<<<wgsBlocks, 256, 0, stream>>>(Wgs);
    k_prep<<<192, 256, 0, stream>>>(W1, W2, W3, Wt);
    k_count<<<edgeBlocks, 256, 0, stream>>>(dst, degi, rank, nedges);
    k_scan1<<<nodeBlocks, 256, 0, stream>>>(degi, rowptr, bsum);
    k_scan2<<<1, 256, 0, stream>>>(bsum, nodeBlocks);
    k_scan3<<<nodeBlocks, 256, 0, stream>>>(rowptr, bsum, degi, dinv);
    k_fill<<<edgeBlocks, 256, 0, stream>>>(src, dst, rank, rowptr, csr_src, nedges);
    k_wgs_e<<<edgeBlocks, 256, 0, stream>>>(src, dst, batch, dinv, Wgs, nedges);
    k_wgs_n<<<nodeBlocks, 256, 0, stream>>>(batch, dinv, Wgs, counts);

    k_mm1<<<mmBlocks, 256, 0, stream>>>(x, Wt, dinv, (ushort_t*)TbA);
    k_fused<<<fusedBlocks, 256, 0, stream>>>(rowptr, csr_src, dinv, TbA,
                                             Wt + 16384, b1, (ushort_t*)TbB);
    k_fused<<<fusedBlocks, 256, 0, stream>>>(rowptr, csr_src, dinv, TbB,
                                             Wt + 32768, b2, (ushort_t*)TbA);
    k_poolmm<<<dim3(NUM_GRAPHS, NPAD / 1024), 256, 0, stream>>>(Wgs, TbA, pooled);
    k_cls<<<NUM_GRAPHS, 128, 0, stream>>>(pooled, counts, b3, C1, bc1, C2, bc2,
                                          (float*)d_out);
}